// Round 4
// baseline (58.808 us; speedup 1.0000x reference)
//
#include <hip/hip_runtime.h>
#include <math.h>

#define POOL 7
#define CCH 256   // channels
#define CANON 224.0f

typedef float nfloat4 __attribute__((ext_vector_type(4)));

__device__ __forceinline__ nfloat4 f4_blend(nfloat4 a, nfloat4 b, float w) {
    return a + (b - a) * w;
}

// Level selection, replicating the reference f32 math exactly.
__device__ __forceinline__ int roi_level(const float* __restrict__ rois,
                                         const float* __restrict__ metas,
                                         int idx, int N) {
    const int b = idx / N;
    const float* box = rois + (size_t)idx * 4;
    const float h = box[2] - box[0];
    const float w = box[3] - box[1];
    const float pad_h = metas[b * 11 + 7];
    const float pad_w = metas[b * 11 + 8];
    const float area = pad_h * pad_w;
    const float lvlf = logf(sqrtf(h * w) / (CANON / sqrtf(area))) / logf(2.0f);
    int lvl = 4 + (int)rintf(lvlf);
    return lvl < 2 ? 2 : (lvl > 5 ? 5 : lvl);
}

// Pre-pass: counting-sort ROI indices into 8 buckets (image b x level) so the
// main kernel's consecutive blocks share a feature map -> L2 locality.
// Intra-bucket order is atomics-nondeterministic, but each ROI writes its own
// output slice, so the final output is order-independent.
__global__ __launch_bounds__(256) void bucket_kernel(
    const float* __restrict__ rois, const float* __restrict__ metas,
    int B, int N, int* __restrict__ perm)
{
    __shared__ int counts[8];
    __shared__ int offs[8];
    const int total = B * N;
    if (threadIdx.x < 8) counts[threadIdx.x] = 0;
    __syncthreads();
    for (int i = threadIdx.x; i < total; i += blockDim.x) {
        const int lvl = roi_level(rois, metas, i, N);
        const int bkt = (i / N) * 4 + (lvl - 2);
        atomicAdd(&counts[bkt], 1);
    }
    __syncthreads();
    if (threadIdx.x == 0) {
        int acc = 0;
        for (int k = 0; k < 8; ++k) { offs[k] = acc; acc += counts[k]; }
    }
    __syncthreads();
    for (int i = threadIdx.x; i < total; i += blockDim.x) {
        const int lvl = roi_level(rois, metas, i, N);
        const int bkt = (i / N) * 4 + (lvl - 2);
        const int pos = atomicAdd(&offs[bkt], 1);
        perm[pos] = i;
    }
}

__global__ __launch_bounds__(256) void roi_align_kernel(
    const float* __restrict__ rois,   // [B,N,4]
    const float* __restrict__ metas,  // [B,11]
    const float* __restrict__ fm2,    // [B,256,256,256]
    const float* __restrict__ fm3,    // [B,128,128,256]
    const float* __restrict__ fm4,    // [B,64,64,256]
    const float* __restrict__ fm5,    // [B,32,32,256]
    const int* __restrict__ perm,     // [B*N] level-grouped ROI order
    float* __restrict__ out,          // [B,N,7,7,256]
    int B, int N)
{
    const int idx = perm[blockIdx.x];      // b*N + n
    const int b = idx / N;

    const float* box = rois + (size_t)idx * 4;
    const float y1 = box[0], x1 = box[1], y2 = box[2], x2 = box[3];
    const float h = y2 - y1;
    const float w = x2 - x1;
    const float pad_h = metas[b * 11 + 7];
    const float pad_w = metas[b * 11 + 8];
    const float area = pad_h * pad_w;
    const float lvlf = logf(sqrtf(h * w) / (CANON / sqrtf(area))) / logf(2.0f);
    int lvl = 4 + (int)rintf(lvlf);
    lvl = lvl < 2 ? 2 : (lvl > 5 ? 5 : lvl);

    const float* fm;
    int H, W;
    if (lvl == 2)      { fm = fm2; H = 256; W = 256; }
    else if (lvl == 3) { fm = fm3; H = 128; W = 128; }
    else if (lvl == 4) { fm = fm4; H = 64;  W = 64;  }
    else               { fm = fm5; H = 32;  W = 32;  }
    const float* img = fm + (size_t)b * H * W * CCH;

    const int tid  = threadIdx.x;
    const int wave = tid >> 6;
    const int lane = tid & 63;

    nfloat4* outp = (nfloat4*)(out + (size_t)idx * (POOL * POOL * CCH));

    const float Hm1 = (float)(H - 1);
    const float Wm1 = (float)(W - 1);

#pragma unroll 4
    for (int it = 0; it < 13; ++it) {
        int p = wave + it * 4;
        p = p > 48 ? 48 : p;
        const int i = p / POOL;
        const int j = p % POOL;
        const float ii = (float)i / 6.0f;
        const float jj = (float)j / 6.0f;
        const float ys = (y1 + ii * h) * Hm1;
        const float xs = (x1 + jj * w) * Wm1;

        const float y0f = floorf(ys);
        const float x0f = floorf(xs);
        const float wy = ys - y0f;
        const float wx = xs - x0f;

        int y0 = (int)y0f; y0 = y0 < 0 ? 0 : (y0 > H - 1 ? H - 1 : y0);
        int x0 = (int)x0f; x0 = x0 < 0 ? 0 : (x0 > W - 1 ? W - 1 : x0);
        int y1i = y0 + 1;  y1i = y1i > H - 1 ? H - 1 : y1i;
        int x1i = x0 + 1;  x1i = x1i > W - 1 ? W - 1 : x1i;

        const nfloat4* tl = (const nfloat4*)(img + ((size_t)(y0  * W + x0 )) * CCH) + lane;
        const nfloat4* tr = (const nfloat4*)(img + ((size_t)(y0  * W + x1i)) * CCH) + lane;
        const nfloat4* bl = (const nfloat4*)(img + ((size_t)(y1i * W + x0 )) * CCH) + lane;
        const nfloat4* br = (const nfloat4*)(img + ((size_t)(y1i * W + x1i)) * CCH) + lane;

        const nfloat4 vtl = *tl;
        const nfloat4 vtr = *tr;
        const nfloat4 vbl = *bl;
        const nfloat4 vbr = *br;

        const nfloat4 top = f4_blend(vtl, vtr, wx);
        const nfloat4 bot = f4_blend(vbl, vbr, wx);
        const nfloat4 res = f4_blend(top, bot, wy);

        __builtin_nontemporal_store(res, &outp[p * 64 + lane]);
    }
}

extern "C" void kernel_launch(void* const* d_in, const int* in_sizes, int n_in,
                              void* d_out, int out_size, void* d_ws, size_t ws_size,
                              hipStream_t stream) {
    const float* rois  = (const float*)d_in[0];
    const float* metas = (const float*)d_in[1];
    const float* fm2   = (const float*)d_in[2];
    const float* fm3   = (const float*)d_in[3];
    const float* fm4   = (const float*)d_in[4];
    const float* fm5   = (const float*)d_in[5];
    float* out = (float*)d_out;
    int* perm = (int*)d_ws;

    const int B = in_sizes[1] / 11;          // img_metas: [B,11]
    const int N = in_sizes[0] / (4 * B);     // rois: [B,N,4]

    bucket_kernel<<<1, 256, 0, stream>>>(rois, metas, B, N, perm);
    roi_align_kernel<<<B * N, 256, 0, stream>>>(rois, metas, fm2, fm3, fm4, fm5,
                                                perm, out, B, N);
}

// Round 5
// 41.203 us; speedup vs baseline: 1.4273x; 1.4273x over previous
//
#include <hip/hip_runtime.h>
#include <math.h>

#define POOL 7
#define CCH 256   // channels
#define CANON 224.0f

typedef float nfloat4 __attribute__((ext_vector_type(4)));

__device__ __forceinline__ nfloat4 f4_blend(nfloat4 a, nfloat4 b, float w) {
    return a + (b - a) * w;
}

// Level selection, replicating the reference f32 math exactly.
__device__ __forceinline__ int roi_level(const float* __restrict__ rois,
                                         const float* __restrict__ metas,
                                         int idx, int N) {
    const int b = idx / N;
    const float* box = rois + (size_t)idx * 4;
    const float h = box[2] - box[0];
    const float w = box[3] - box[1];
    const float pad_h = metas[b * 11 + 7];
    const float pad_w = metas[b * 11 + 8];
    const float area = pad_h * pad_w;
    const float lvlf = logf(sqrtf(h * w) / (CANON / sqrtf(area))) / logf(2.0f);
    int lvl = 4 + (int)rintf(lvlf);
    return lvl < 2 ? 2 : (lvl > 5 ? 5 : lvl);
}

// Single-block pre-pass: counting-sort ROI indices into 64 buckets
// (image b x level x y-band) entirely in LDS, writing a permutation with the
// level encoded in the high bits. Intra-bucket order is atomics-
// nondeterministic, but each ROI writes a private output slice, so the final
// output is order-independent.
__global__ __launch_bounds__(1024) void bucket_kernel(
    const float* __restrict__ rois, const float* __restrict__ metas,
    int B, int N, int* __restrict__ perm)
{
    __shared__ int counts[64];
    __shared__ int offs[64];
    const int total = B * N;
    const int tid = threadIdx.x;
    if (tid < 64) counts[tid] = 0;
    __syncthreads();

    for (int i = tid; i < total; i += 1024) {
        const int b = i / N;
        const int lvl = roi_level(rois, metas, i, N);
        const float yc = 0.5f * (rois[(size_t)i * 4 + 0] + rois[(size_t)i * 4 + 2]);
        int band = (int)(yc * 8.0f); band = band < 0 ? 0 : (band > 7 ? 7 : band);
        const int key = b * 32 + (lvl - 2) * 8 + band;
        atomicAdd(&counts[key], 1);
    }
    __syncthreads();
    if (tid == 0) {
        int acc = 0;
        for (int k = 0; k < 64; ++k) { offs[k] = acc; acc += counts[k]; }
    }
    __syncthreads();
    for (int i = tid; i < total; i += 1024) {
        const int b = i / N;
        const int lvl = roi_level(rois, metas, i, N);
        const float yc = 0.5f * (rois[(size_t)i * 4 + 0] + rois[(size_t)i * 4 + 2]);
        int band = (int)(yc * 8.0f); band = band < 0 ? 0 : (band > 7 ? 7 : band);
        const int key = b * 32 + (lvl - 2) * 8 + band;
        const int pos = atomicAdd(&offs[key], 1);
        perm[pos] = i | (lvl << 24);       // encode level: main kernel skips logf
    }
}

__global__ __launch_bounds__(256) void roi_align_kernel(
    const float* __restrict__ rois,   // [B,N,4]
    const float* __restrict__ fm2,    // [B,256,256,256]
    const float* __restrict__ fm3,    // [B,128,128,256]
    const float* __restrict__ fm4,    // [B,64,64,256]
    const float* __restrict__ fm5,    // [B,32,32,256]
    const int* __restrict__ perm,     // [B*N] sorted (image,level,y-band) order
    float* __restrict__ out,          // [B,N,7,7,256]
    int B, int N)
{
    // Inverse round-robin XCD mapping (bijective, m204): block b runs on
    // XCD (b&7); give that XCD the (b&7)-th CONTIGUOUS chunk of the sorted
    // order, so co-resident blocks on one XCD share a feature-map region.
    const int total = B * N;
    const int q = total >> 3, r = total & 7;
    const int k = blockIdx.x & 7, j = blockIdx.x >> 3;
    const int p = (k < r) ? k * (q + 1) + j : r * (q + 1) + (k - r) * q + j;

    const int e = perm[p];
    const int idx = e & 0xFFFFFF;          // b*N + n
    const int lvl = e >> 24;
    const int b = idx / N;

    const float* box = rois + (size_t)idx * 4;
    const float y1 = box[0], x1 = box[1], y2 = box[2], x2 = box[3];
    const float h = y2 - y1;
    const float w = x2 - x1;

    const float* fm;
    int H, W;
    if (lvl == 2)      { fm = fm2; H = 256; W = 256; }
    else if (lvl == 3) { fm = fm3; H = 128; W = 128; }
    else if (lvl == 4) { fm = fm4; H = 64;  W = 64;  }
    else               { fm = fm5; H = 32;  W = 32;  }
    const float* img = fm + (size_t)b * H * W * CCH;

    const int tid  = threadIdx.x;
    const int wave = tid >> 6;
    const int lane = tid & 63;

    nfloat4* outp = (nfloat4*)(out + (size_t)idx * (POOL * POOL * CCH));

    const float Hm1 = (float)(H - 1);
    const float Wm1 = (float)(W - 1);

#pragma unroll 4
    for (int it = 0; it < 13; ++it) {
        int pp = wave + it * 4;
        pp = pp > 48 ? 48 : pp;
        const int i = pp / POOL;
        const int jx = pp % POOL;
        const float ii = (float)i / 6.0f;
        const float jj = (float)jx / 6.0f;
        const float ys = (y1 + ii * h) * Hm1;
        const float xs = (x1 + jj * w) * Wm1;

        const float y0f = floorf(ys);
        const float x0f = floorf(xs);
        const float wy = ys - y0f;
        const float wx = xs - x0f;

        int y0 = (int)y0f; y0 = y0 < 0 ? 0 : (y0 > H - 1 ? H - 1 : y0);
        int x0 = (int)x0f; x0 = x0 < 0 ? 0 : (x0 > W - 1 ? W - 1 : x0);
        int y1i = y0 + 1;  y1i = y1i > H - 1 ? H - 1 : y1i;
        int x1i = x0 + 1;  x1i = x1i > W - 1 ? W - 1 : x1i;

        const nfloat4* tl = (const nfloat4*)(img + ((size_t)(y0  * W + x0 )) * CCH) + lane;
        const nfloat4* tr = (const nfloat4*)(img + ((size_t)(y0  * W + x1i)) * CCH) + lane;
        const nfloat4* bl = (const nfloat4*)(img + ((size_t)(y1i * W + x0 )) * CCH) + lane;
        const nfloat4* br = (const nfloat4*)(img + ((size_t)(y1i * W + x1i)) * CCH) + lane;

        const nfloat4 vtl = *tl;
        const nfloat4 vtr = *tr;
        const nfloat4 vbl = *bl;
        const nfloat4 vbr = *br;

        const nfloat4 top = f4_blend(vtl, vtr, wx);
        const nfloat4 bot = f4_blend(vbl, vbr, wx);
        const nfloat4 res = f4_blend(top, bot, wy);

        __builtin_nontemporal_store(res, &outp[pp * 64 + lane]);
    }
}

extern "C" void kernel_launch(void* const* d_in, const int* in_sizes, int n_in,
                              void* d_out, int out_size, void* d_ws, size_t ws_size,
                              hipStream_t stream) {
    const float* rois  = (const float*)d_in[0];
    const float* metas = (const float*)d_in[1];
    const float* fm2   = (const float*)d_in[2];
    const float* fm3   = (const float*)d_in[3];
    const float* fm4   = (const float*)d_in[4];
    const float* fm5   = (const float*)d_in[5];
    float* out = (float*)d_out;
    int* perm = (int*)d_ws;

    const int B = in_sizes[1] / 11;          // img_metas: [B,11]
    const int N = in_sizes[0] / (4 * B);     // rois: [B,N,4]

    bucket_kernel<<<1, 1024, 0, stream>>>(rois, metas, B, N, perm);
    roi_align_kernel<<<B * N, 256, 0, stream>>>(rois, fm2, fm3, fm4, fm5,
                                                perm, out, B, N);
}

// Round 6
// 38.690 us; speedup vs baseline: 1.5200x; 1.0649x over previous
//
#include <hip/hip_runtime.h>
#include <math.h>

#define POOL 7
#define CCH 256   // channels
#define CANON 224.0f
#define MAX_LDS_KEYS 8192

typedef float nfloat4 __attribute__((ext_vector_type(4)));

// ---- level selection, replicating reference f32 math exactly ----
__device__ __forceinline__ int roi_level_of(const float* __restrict__ rois,
                                            const float* __restrict__ metas,
                                            int i, int N) {
    const int b = i / N;
    const float* box = rois + (size_t)i * 4;
    const float h = box[2] - box[0];
    const float w = box[3] - box[1];
    const float pad_h = metas[b * 11 + 7];
    const float pad_w = metas[b * 11 + 8];
    const float area = pad_h * pad_w;
    const float lvlf = logf(sqrtf(h * w) / (CANON / sqrtf(area))) / logf(2.0f);
    int lvl = 4 + (int)rintf(lvlf);
    return lvl < 2 ? 2 : (lvl > 5 ? 5 : lvl);
}

__device__ __forceinline__ int bucket_key(const float* __restrict__ rois,
                                          const float* __restrict__ metas,
                                          int i, int N, int* lvl_out) {
    const int lvl = roi_level_of(rois, metas, i, N);
    *lvl_out = lvl;
    const float yc = 0.5f * (rois[(size_t)i * 4 + 0] + rois[(size_t)i * 4 + 2]);
    int band = (int)(yc * 16.0f); band = band < 0 ? 0 : (band > 15 ? 15 : band);
    const int b = i / N;
    return ((b & 1) * 64) + (lvl - 2) * 16 + band;   // 0..127
}

// Single-block counting sort into 128 buckets (image&1 x level x y-band16).
// Keys cached in LDS (logf computed once); 128-wide parallel scan.
// Intra-bucket order is atomics-nondeterministic, but each ROI writes a
// private output slice, so the final output is order-independent.
__global__ __launch_bounds__(1024) void bucket_kernel(
    const float* __restrict__ rois, const float* __restrict__ metas,
    int B, int N, int* __restrict__ perm)
{
    __shared__ int counts[128];
    __shared__ int offs[128];
    __shared__ int excl[128];
    __shared__ unsigned short keys[MAX_LDS_KEYS];
    const int total = B * N;
    const int tid = threadIdx.x;
    const bool cache = (total <= MAX_LDS_KEYS);

    if (tid < 128) counts[tid] = 0;
    __syncthreads();

    for (int i = tid; i < total; i += 1024) {
        int lvl;
        const int key = bucket_key(rois, metas, i, N, &lvl);
        if (cache) keys[i] = (unsigned short)(key | (lvl << 8));
        atomicAdd(&counts[key], 1);
    }
    __syncthreads();

    // inclusive Hillis-Steele scan over 128, then shift to exclusive
    if (tid < 128) offs[tid] = counts[tid];
    __syncthreads();
    for (int d = 1; d < 128; d <<= 1) {
        int v = 0;
        if (tid < 128 && tid >= d) v = offs[tid - d];
        __syncthreads();
        if (tid < 128 && tid >= d) offs[tid] += v;
        __syncthreads();
    }
    if (tid < 128) excl[tid] = (tid == 0) ? 0 : offs[tid - 1];
    __syncthreads();
    if (tid < 128) offs[tid] = excl[tid];
    __syncthreads();

    for (int i = tid; i < total; i += 1024) {
        int key, lvl;
        if (cache) { const int e = keys[i]; key = e & 0xFF; lvl = e >> 8; }
        else       { key = bucket_key(rois, metas, i, N, &lvl); }
        const int pos = atomicAdd(&offs[key], 1);
        perm[pos] = i | (lvl << 24);
    }
}

// 7 waves x 7 points: wave = output row i (y-math hoisted), 7 x-samples each.
__global__ __launch_bounds__(448) void roi_align_kernel(
    const float* __restrict__ rois,   // [B,N,4]
    const float* __restrict__ fm2,    // [B,256,256,256]
    const float* __restrict__ fm3,    // [B,128,128,256]
    const float* __restrict__ fm4,    // [B,64,64,256]
    const float* __restrict__ fm5,    // [B,32,32,256]
    const int* __restrict__ perm,     // [B*N] sorted (image,level,y-band) order
    float* __restrict__ out,          // [B,N,7,7,256]
    int B, int N)
{
    // Bijective inverse round-robin XCD mapping: block b runs on XCD (b&7);
    // give that XCD the (b&7)-th contiguous chunk of the sorted order.
    const int total = B * N;
    const int q = total >> 3, r = total & 7;
    const int k = blockIdx.x & 7, jb = blockIdx.x >> 3;
    const int p = (k < r) ? k * (q + 1) + jb : r * (q + 1) + (k - r) * q + jb;

    const int e = perm[p];
    const int idx = e & 0xFFFFFF;          // b*N + n
    const int lvl = e >> 24;
    const int b = idx / N;

    const float* box = rois + (size_t)idx * 4;
    const float y1 = box[0], x1 = box[1], y2 = box[2], x2 = box[3];
    const float h = y2 - y1;
    const float w = x2 - x1;

    const float* fm;
    int H, W;
    if (lvl == 2)      { fm = fm2; H = 256; W = 256; }
    else if (lvl == 3) { fm = fm3; H = 128; W = 128; }
    else if (lvl == 4) { fm = fm4; H = 64;  W = 64;  }
    else               { fm = fm5; H = 32;  W = 32;  }
    const float* img = fm + (size_t)b * H * W * CCH;

    const int wave = threadIdx.x >> 6;     // 0..6 = output row i
    const int lane = threadIdx.x & 63;     // 4 channels each

    const float Hm1 = (float)(H - 1);
    const float Wm1 = (float)(W - 1);

    // y-side bilinear (one row per wave)
    const float ii = (float)wave / 6.0f;
    const float ys = (y1 + ii * h) * Hm1;
    const float y0f = floorf(ys);
    const float wy = ys - y0f;
    int y0 = (int)y0f; y0 = y0 < 0 ? 0 : (y0 > H - 1 ? H - 1 : y0);
    int y1i = y0 + 1;  y1i = y1i > H - 1 ? H - 1 : y1i;

    const nfloat4* rowT = (const nfloat4*)(img + (size_t)y0  * W * CCH) + lane;
    const nfloat4* rowB = (const nfloat4*)(img + (size_t)y1i * W * CCH) + lane;
    nfloat4* outp = (nfloat4*)(out + (size_t)idx * (POOL * POOL * CCH))
                    + wave * (POOL * 64) + lane;

#pragma unroll
    for (int j = 0; j < POOL; ++j) {
        const float jj = (float)j / 6.0f;
        const float xs = (x1 + jj * w) * Wm1;
        const float x0f = floorf(xs);
        const float wx = xs - x0f;
        int x0 = (int)x0f; x0 = x0 < 0 ? 0 : (x0 > W - 1 ? W - 1 : x0);
        int x1i = x0 + 1;  x1i = x1i > W - 1 ? W - 1 : x1i;

        const nfloat4 vtl = rowT[(size_t)x0  * 64];
        const nfloat4 vtr = rowT[(size_t)x1i * 64];
        const nfloat4 vbl = rowB[(size_t)x0  * 64];
        const nfloat4 vbr = rowB[(size_t)x1i * 64];

        const nfloat4 top = vtl + (vtr - vtl) * wx;
        const nfloat4 bot = vbl + (vbr - vbl) * wx;
        const nfloat4 res = top + (bot - top) * wy;

        __builtin_nontemporal_store(res, outp + j * 64);
    }
}

extern "C" void kernel_launch(void* const* d_in, const int* in_sizes, int n_in,
                              void* d_out, int out_size, void* d_ws, size_t ws_size,
                              hipStream_t stream) {
    const float* rois  = (const float*)d_in[0];
    const float* metas = (const float*)d_in[1];
    const float* fm2   = (const float*)d_in[2];
    const float* fm3   = (const float*)d_in[3];
    const float* fm4   = (const float*)d_in[4];
    const float* fm5   = (const float*)d_in[5];
    float* out = (float*)d_out;
    int* perm = (int*)d_ws;

    const int B = in_sizes[1] / 11;          // img_metas: [B,11]
    const int N = in_sizes[0] / (4 * B);     // rois: [B,N,4]

    bucket_kernel<<<1, 1024, 0, stream>>>(rois, metas, B, N, perm);
    roi_align_kernel<<<B * N, 448, 0, stream>>>(rois, fm2, fm3, fm4, fm5,
                                                perm, out, B, N);
}